// Round 8
// baseline (28.271 us; speedup 1.0000x reference)
//
#include <hip/hip_runtime.h>

#define H 512
#define W 512

typedef float f32x4 __attribute__((ext_vector_type(4)));

// DPP wave rotates: *_ror moves data toward HIGHER lanes (dst[i]=src[i-1]).
__device__ __forceinline__ float dpp_left1(float v) {   // dst[i] = src[(i-1) & 63]
    return __int_as_float(__builtin_amdgcn_update_dpp(
        0, __float_as_int(v), 0x13C /*wave_ror:1*/, 0xF, 0xF, false));
}
__device__ __forceinline__ float dpp_right1(float v) {  // dst[i] = src[(i+1) & 63]
    return __int_as_float(__builtin_amdgcn_update_dpp(
        0, __float_as_int(v), 0x134 /*wave_rol:1*/, 0xF, 0xF, false));
}

// 8 output rows per wave (reads 14 rows -> 1.75x read redundancy, was 2.5x).
// 4 waves/block -> 32-row band; 768 blocks = 8 XCDs x 96.
__global__ __launch_bounds__(256, 3) void lvar_kernel(const float* __restrict__ x,
                                                      float* __restrict__ out) {
    const int lane = threadIdx.x;                 // 0..63, owns cols 8*lane..8*lane+7
    const int wv   = threadIdx.y;                 // 0..3
    const int bid  = blockIdx.x;
    const int wg   = (bid & 7) * 96 + (bid >> 3); // XCD-bijective (768 % 8 == 0)
    const int img  = wg >> 4;                     // 0..47
    const int band = wg & 15;
    const int R    = band * 32 + wv * 8;          // this wave's first output row

    const float* __restrict__ xim = x + (size_t)img * (H * W);
    float* __restrict__ oim = out + (size_t)img * (H * W);
    const int c8 = lane * 8;
    const float inv = 1.0f / 49.0f;

    float s[8], q[8];        // running 7-row vertical sums of x, x^2
    float keep[7][8];        // rows R-3..R+3 (subtracted at steps 1..7)

    #pragma unroll
    for (int c = 0; c < 8; ++c) { s[c] = 0.f; q[c] = 0.f; }

    auto loadrow = [&](int r, float v[8]) {
        const int gr = r & (H - 1);
        const f32x4* p = (const f32x4*)(xim + gr * W + c8);
        const f32x4 a = p[0], b = p[1];
        v[0]=a.x; v[1]=a.y; v[2]=a.z; v[3]=a.w;
        v[4]=b.x; v[5]=b.y; v[6]=b.z; v[7]=b.w;
    };

    auto emit = [&](int r) {
        float Wn[14], W2[14];
        #pragma unroll
        for (int t = 0; t < 3; ++t) {             // circular col halo via DPP
            Wn[t]      = dpp_left1(s[5 + t]);     // left neighbor's cols 5..7
            W2[t]      = dpp_left1(q[5 + t]);
            Wn[11 + t] = dpp_right1(s[t]);        // right neighbor's cols 0..2
            W2[11 + t] = dpp_right1(q[t]);
        }
        #pragma unroll
        for (int c = 0; c < 8; ++c) { Wn[3 + c] = s[c]; W2[3 + c] = q[c]; }

        float res[8];
        float hs = Wn[0]+Wn[1]+Wn[2]+Wn[3]+Wn[4]+Wn[5]+Wn[6];
        float hq = W2[0]+W2[1]+W2[2]+W2[3]+W2[4]+W2[5]+W2[6];
        { const float m = hs * inv; res[0] = fmaf(-m, m, hq * inv); }
        #pragma unroll
        for (int k = 1; k < 8; ++k) {
            hs += Wn[k + 6] - Wn[k - 1];
            hq += W2[k + 6] - W2[k - 1];
            const float m = hs * inv;
            res[k] = fmaf(-m, m, hq * inv);
        }
        f32x4* qp = (f32x4*)(oim + r * W + c8);
        f32x4 o0 = {res[0], res[1], res[2], res[3]};
        f32x4 o1 = {res[4], res[5], res[6], res[7]};
        __builtin_nontemporal_store(o0, qp);      // write-once output
        __builtin_nontemporal_store(o1, qp + 1);
    };

    auto update = [&](const float nv[8], const float old[8]) {
        #pragma unroll
        for (int c = 0; c < 8; ++c) {
            s[c] += nv[c] - old[c];
            q[c] = fmaf(nv[c], nv[c], q[c]);
            q[c] = fmaf(-old[c], old[c], q[c]);
        }
    };

    // ---- init: rows R-3 .. R+3 into keep[], accumulate ----
    #pragma unroll
    for (int k = 0; k < 7; ++k) {
        loadrow(R - 3 + k, keep[k]);
        #pragma unroll
        for (int c = 0; c < 8; ++c) {
            s[c] += keep[k][c];
            q[c] = fmaf(keep[k][c], keep[k][c], q[c]);
        }
    }

    // ---- 8 output rows, loads pipelined one emit ahead (all indices static) ----
    float va[8], vb[8];
    loadrow(R + 4, va);
    emit(R);
    loadrow(R + 5, vb);  update(va, keep[0]);  emit(R + 1);
    loadrow(R + 6, va);  update(vb, keep[1]);  emit(R + 2);
    loadrow(R + 7, vb);  update(va, keep[2]);  emit(R + 3);
    loadrow(R + 8, va);  update(vb, keep[3]);  emit(R + 4);
    loadrow(R + 9, vb);  update(va, keep[4]);  emit(R + 5);
    loadrow(R + 10, va); update(vb, keep[5]);  emit(R + 6);
    update(va, keep[6]); emit(R + 7);
}

extern "C" void kernel_launch(void* const* d_in, const int* in_sizes, int n_in,
                              void* d_out, int out_size, void* d_ws, size_t ws_size,
                              hipStream_t stream) {
    const float* x = (const float*)d_in[0];
    float* out = (float*)d_out;
    const int nimg = in_sizes[0] / (H * W);       // 48
    dim3 grid(nimg * 16);                         // 768 blocks (8 | 768)
    dim3 block(64, 4);
    lvar_kernel<<<grid, block, 0, stream>>>(x, out);
}

// Round 9
// 27.150 us; speedup vs baseline: 1.0413x; 1.0413x over previous
//
#include <hip/hip_runtime.h>

#define H 512
#define W 512

typedef float f32x4 __attribute__((ext_vector_type(4)));

// DPP wave rotates: *_ror moves data toward HIGHER lanes (dst[i]=src[i-1]).
__device__ __forceinline__ float dpp_left1(float v) {   // dst[i] = src[(i-1) & 63]
    return __int_as_float(__builtin_amdgcn_update_dpp(
        0, __float_as_int(v), 0x13C /*wave_ror:1*/, 0xF, 0xF, false));
}
__device__ __forceinline__ float dpp_right1(float v) {  // dst[i] = src[(i+1) & 63]
    return __int_as_float(__builtin_amdgcn_update_dpp(
        0, __float_as_int(v), 0x134 /*wave_rol:1*/, 0xF, 0xF, false));
}

// 4 output rows/wave (R6 structure), but ALL 10 input rows' loads issued as one
// upfront burst so the wave's entire HBM demand is in flight before consumption.
__global__ __launch_bounds__(256, 4) void lvar_kernel(const float* __restrict__ x,
                                                      float* __restrict__ out) {
    const int lane = threadIdx.x;                 // 0..63, owns cols 8*lane..8*lane+7
    const int wv   = threadIdx.y;                 // 0..3
    const int bid  = blockIdx.x;
    const int wg   = (bid & 7) * 192 + (bid >> 3);// XCD-bijective (1536 % 8 == 0)
    const int img  = wg >> 5;                     // 0..47
    const int band = wg & 31;
    const int R    = band * 16 + wv * 4;          // this wave's first output row

    const float* __restrict__ xim = x + (size_t)img * (H * W);
    float* __restrict__ oim = out + (size_t)img * (H * W);
    const int c8 = lane * 8;
    const float inv = 1.0f / 49.0f;

    auto loadrow = [&](int r, float v[8]) {
        const int gr = r & (H - 1);
        const f32x4* p = (const f32x4*)(xim + gr * W + c8);
        const f32x4 a = p[0], b = p[1];
        v[0]=a.x; v[1]=a.y; v[2]=a.z; v[3]=a.w;
        v[4]=b.x; v[5]=b.y; v[6]=b.z; v[7]=b.w;
    };

    // ---- burst: issue ALL 10 row loads before any consumption ----
    float k0[8], k1[8], k2[8];          // rows R-3..R-1 (kept for subtraction)
    float a0[8], a1[8], a2[8], a3[8];   // rows R..R+3   (add-only)
    float t4[8], t5[8], t6[8];          // rows R+4..R+6 (added at steps 1..3)
    loadrow(R - 3, k0); loadrow(R - 2, k1); loadrow(R - 1, k2);
    loadrow(R + 0, a0); loadrow(R + 1, a1); loadrow(R + 2, a2); loadrow(R + 3, a3);
    loadrow(R + 4, t4); loadrow(R + 5, t5); loadrow(R + 6, t6);

    float s[8], q[8];
    #pragma unroll
    for (int c = 0; c < 8; ++c) { s[c] = 0.f; q[c] = 0.f; }

    auto acc = [&](const float v[8]) {
        #pragma unroll
        for (int c = 0; c < 8; ++c) {
            s[c] += v[c];
            q[c] = fmaf(v[c], v[c], q[c]);
        }
    };
    auto update = [&](const float nv[8], const float old[8]) {
        #pragma unroll
        for (int c = 0; c < 8; ++c) {
            s[c] += nv[c] - old[c];
            q[c] = fmaf(nv[c], nv[c], q[c]);
            q[c] = fmaf(-old[c], old[c], q[c]);
        }
    };

    auto emit = [&](int r) {
        float Wn[14], W2[14];
        #pragma unroll
        for (int t = 0; t < 3; ++t) {             // circular col halo via DPP
            Wn[t]      = dpp_left1(s[5 + t]);     // left neighbor's cols 5..7
            W2[t]      = dpp_left1(q[5 + t]);
            Wn[11 + t] = dpp_right1(s[t]);        // right neighbor's cols 0..2
            W2[11 + t] = dpp_right1(q[t]);
        }
        #pragma unroll
        for (int c = 0; c < 8; ++c) { Wn[3 + c] = s[c]; W2[3 + c] = q[c]; }

        float res[8];
        float hs = Wn[0]+Wn[1]+Wn[2]+Wn[3]+Wn[4]+Wn[5]+Wn[6];
        float hq = W2[0]+W2[1]+W2[2]+W2[3]+W2[4]+W2[5]+W2[6];
        { const float m = hs * inv; res[0] = fmaf(-m, m, hq * inv); }
        #pragma unroll
        for (int k = 1; k < 8; ++k) {
            hs += Wn[k + 6] - Wn[k - 1];
            hq += W2[k + 6] - W2[k - 1];
            const float m = hs * inv;
            res[k] = fmaf(-m, m, hq * inv);
        }
        f32x4* qp = (f32x4*)(oim + r * W + c8);
        f32x4 o0 = {res[0], res[1], res[2], res[3]};
        f32x4 o1 = {res[4], res[5], res[6], res[7]};
        __builtin_nontemporal_store(o0, qp);      // write-once output
        __builtin_nontemporal_store(o1, qp + 1);
    };

    // ---- consume in load order (minimal vmcnt waits) ----
    acc(k0); acc(k1); acc(k2); acc(a0); acc(a1); acc(a2); acc(a3);
    emit(R);
    update(t4, k0); emit(R + 1);
    update(t5, k1); emit(R + 2);
    update(t6, k2); emit(R + 3);
}

extern "C" void kernel_launch(void* const* d_in, const int* in_sizes, int n_in,
                              void* d_out, int out_size, void* d_ws, size_t ws_size,
                              hipStream_t stream) {
    const float* x = (const float*)d_in[0];
    float* out = (float*)d_out;
    const int nimg = in_sizes[0] / (H * W);       // 48
    dim3 grid(nimg * 32);                         // 1536 blocks (8 | 1536)
    dim3 block(64, 4);
    lvar_kernel<<<grid, block, 0, stream>>>(x, out);
}